// Round 4
// baseline (1409.416 us; speedup 1.0000x reference)
//
#include <hip/hip_runtime.h>
#include <hip/hip_bf16.h>
#include <stdint.h>

// Problem constants (SNNExoplanetDetector): B=256 batch, T=1000 steps,
// F=128 input feats, H=256 hidden, O=2 outputs.
constexpr int B = 256, T = 1000, F = 128, H = 256, O = 2;
constexpr float DT_TAU_MEM = 0.1f;   // DT * TAU_MEM_INV
constexpr float SYN_DECAY  = 0.8f;   // 1 - DT * TAU_SYN_INV
constexpr float V_THRESH   = 1.0f;

// ---------------------------------------------------------------------------
// Storage-type adapters for xw (fp32 if workspace fits it, else bf16).
// ---------------------------------------------------------------------------
__device__ inline unsigned short f2bf_raw(float f) {
  __hip_bfloat16 b = __float2bfloat16(f);
  return *reinterpret_cast<unsigned short*>(&b);
}

template <typename XT> struct XConv;
template <> struct XConv<float> {
  static __device__ inline float4 load4(const float* p) {
    return *reinterpret_cast<const float4*>(p);
  }
  static __device__ inline void store4(float* p, float a, float b, float c, float d) {
    *reinterpret_cast<float4*>(p) = make_float4(a, b, c, d);
  }
};
template <> struct XConv<__hip_bfloat16> {
  static __device__ inline float4 load4(const __hip_bfloat16* p) {
    ushort4 u = *reinterpret_cast<const ushort4*>(p);
    return make_float4(__uint_as_float((unsigned)u.x << 16),
                       __uint_as_float((unsigned)u.y << 16),
                       __uint_as_float((unsigned)u.z << 16),
                       __uint_as_float((unsigned)u.w << 16));
  }
  static __device__ inline void store4(__hip_bfloat16* p, float a, float b, float c, float d) {
    ushort4 u = make_ushort4(f2bf_raw(a), f2bf_raw(b), f2bf_raw(c), f2bf_raw(d));
    *reinterpret_cast<ushort4*>(p) = u;
  }
};

// ---------------------------------------------------------------------------
// Transpose w_rec [h][k] -> wT [k][h]  (so a spike k gathers a contiguous row)
// ---------------------------------------------------------------------------
__global__ void transpose_wrec(const float* __restrict__ w, float* __restrict__ wT) {
  int k = blockIdx.x;
  int h = threadIdx.x;
  wT[k * H + h] = w[h * H + k];
}

// ---------------------------------------------------------------------------
// GEMM: xw[m][n] = sum_k x[m][k] * w_in[n][k];  M = B*T = 256000, K=128, N=256
// (unchanged)
// ---------------------------------------------------------------------------
template <typename XT>
__global__ __launch_bounds__(256) void gemm_xw(const float* __restrict__ x,
                                               const float* __restrict__ w_in,
                                               XT* __restrict__ xw) {
  constexpr int K = 128;
  constexpr int SA = 68;  // padded LDS row stride (floats), multiple of 4 for b128
  __shared__ float As[K][SA];
  __shared__ float Bs[K][SA];

  const int m0 = blockIdx.x * 64;
  const int n0 = blockIdx.y * 64;
  const int tid = threadIdx.x;

  {
    const int r  = tid >> 2;   // 0..63  (row within tile)
    const int cq = tid & 3;    // 0..3   (float4 phase)
    const float* xa = x    + (size_t)(m0 + r) * K;
    const float* xb = w_in + (size_t)(n0 + r) * K;
#pragma unroll
    for (int j = 0; j < 8; ++j) {
      const int c = (cq + (j << 2)) << 2;  // 0..124, step covers all 128
      float4 av = *reinterpret_cast<const float4*>(xa + c);
      float4 bv = *reinterpret_cast<const float4*>(xb + c);
      As[c + 0][r] = av.x; As[c + 1][r] = av.y; As[c + 2][r] = av.z; As[c + 3][r] = av.w;
      Bs[c + 0][r] = bv.x; Bs[c + 1][r] = bv.y; Bs[c + 2][r] = bv.z; Bs[c + 3][r] = bv.w;
    }
  }
  __syncthreads();

  const int tn = (tid & 15) << 2;  // 0,4,...,60
  const int tm = (tid >> 4) << 2;  // 0,4,...,60
  float acc[4][4] = {};

#pragma unroll 16
  for (int k = 0; k < K; ++k) {
    float4 a = *reinterpret_cast<const float4*>(&As[k][tm]);
    float4 b = *reinterpret_cast<const float4*>(&Bs[k][tn]);
    acc[0][0] += a.x * b.x; acc[0][1] += a.x * b.y; acc[0][2] += a.x * b.z; acc[0][3] += a.x * b.w;
    acc[1][0] += a.y * b.x; acc[1][1] += a.y * b.y; acc[1][2] += a.y * b.z; acc[1][3] += a.y * b.w;
    acc[2][0] += a.z * b.x; acc[2][1] += a.z * b.y; acc[2][2] += a.z * b.z; acc[2][3] += a.z * b.w;
    acc[3][0] += a.w * b.x; acc[3][1] += a.w * b.y; acc[3][2] += a.w * b.z; acc[3][3] += a.w * b.w;
  }

#pragma unroll
  for (int im = 0; im < 4; ++im) {
    XT* p = xw + (size_t)(m0 + tm + im) * H + (n0 + tn);
    XConv<XT>::store4(p, acc[im][0], acc[im][1], acc[im][2], acc[im][3]);
  }
}

// ---------------------------------------------------------------------------
// LIF scan, single-wave design (see Round-0 notes). Round-4 change:
//   the xw prefetch load is issued AFTER the first global wT chunk, pinned
//   with sched_barrier(0). vmcnt retires in order, so an xb issued at the
//   loop top forced a full-HBM-latency drain inside the gather's counted
//   vmcnt wait every step (~500-800cy). Issued after the gather loads, xb
//   is younger than everything the gather waits on; it retires lazily
//   during the NEXT iteration (~2500cy of slack).
// ---------------------------------------------------------------------------

// Extract one row index from a 2x64-bit mask stream (wave-uniform -> SALU).
// ctz guard: OR with the TOP bit -- leaves the lowest set bit of any nonzero
// mask untouched; empty mask decodes to a dummy in-bounds row, predicated off.
#define EX1(X, Y, ROW) do {                                         \
    uint64_t sel_ = (X) ? (X) : (Y);                                \
    int p_ = __builtin_ctzll(sel_ | 0x8000000000000000ull);         \
    ROW = ((p_ & 31) << 2) | (p_ >> 5) | ((X) ? 0 : 2);             \
    uint64_t cl_ = sel_ & (sel_ - 1ull);                            \
    Y = (X) ? (Y) : cl_;                                            \
    X = (X) ? cl_ : (X);                                            \
  } while (0)

// Extract up to 8 rows, issue 8 float4 loads from BASE[row<<6], preds from N.
#define CHUNK8(X, Y, N, BASE, V0,V1,V2,V3,V4,V5,V6,V7, P0,P1,P2,P3,P4,P5,P6,P7) do { \
    int r_;                                                          \
    P0 = ((N) > 0) ? 1.f : 0.f; EX1(X, Y, r_); V0 = (BASE)[r_ << 6]; \
    P1 = ((N) > 1) ? 1.f : 0.f; EX1(X, Y, r_); V1 = (BASE)[r_ << 6]; \
    P2 = ((N) > 2) ? 1.f : 0.f; EX1(X, Y, r_); V2 = (BASE)[r_ << 6]; \
    P3 = ((N) > 3) ? 1.f : 0.f; EX1(X, Y, r_); V3 = (BASE)[r_ << 6]; \
    P4 = ((N) > 4) ? 1.f : 0.f; EX1(X, Y, r_); V4 = (BASE)[r_ << 6]; \
    P5 = ((N) > 5) ? 1.f : 0.f; EX1(X, Y, r_); V5 = (BASE)[r_ << 6]; \
    P6 = ((N) > 6) ? 1.f : 0.f; EX1(X, Y, r_); V6 = (BASE)[r_ << 6]; \
    P7 = ((N) > 7) ? 1.f : 0.f; EX1(X, Y, r_); V7 = (BASE)[r_ << 6]; \
  } while (0)

#define ACC8(V0,V1,V2,V3,V4,V5,V6,V7, P0,P1,P2,P3,P4,P5,P6,P7) do {  \
    r0 += P0 * V0.x; r1 += P0 * V0.y; r2 += P0 * V0.z; r3 += P0 * V0.w; \
    r0 += P1 * V1.x; r1 += P1 * V1.y; r2 += P1 * V1.z; r3 += P1 * V1.w; \
    r0 += P2 * V2.x; r1 += P2 * V2.y; r2 += P2 * V2.z; r3 += P2 * V2.w; \
    r0 += P3 * V3.x; r1 += P3 * V3.y; r2 += P3 * V3.z; r3 += P3 * V3.w; \
    r0 += P4 * V4.x; r1 += P4 * V4.y; r2 += P4 * V4.z; r3 += P4 * V4.w; \
    r0 += P5 * V5.x; r1 += P5 * V5.y; r2 += P5 * V5.z; r3 += P5 * V5.w; \
    r0 += P6 * V6.x; r1 += P6 * V6.y; r2 += P6 * V6.z; r3 += P6 * V6.w; \
    r0 += P7 * V7.x; r1 += P7 * V7.y; r2 += P7 * V7.z; r3 += P7 * V7.w; \
  } while (0)

template <typename XT>
__global__ __launch_bounds__(64, 1) void scan_lif(const XT* __restrict__ xw,
                                                  const float* __restrict__ wT,
                                                  const float* __restrict__ fc_w,
                                                  const float* __restrict__ fc_b,
                                                  float* __restrict__ out) {
  const int b  = blockIdx.x;
  const int ln = threadIdx.x;  // lane 0..63; owns neurons 4ln..4ln+3

  // Rows 0..127 of wT, exact fp32, laid out [row][lane] as float4.
  __shared__ float4 wlds[128 * 64];  // 128 KiB

  const float4* wTf4 = reinterpret_cast<const float4*>(wT);
  for (int i = ln; i < 128 * 64; i += 64) wlds[i] = wTf4[i];
  __syncthreads();

  const float4* gB = wTf4 + 128 * 64 + ln;  // rows 128..255 via gB[row<<6]
  const float4* lB = &wlds[ln];             // rows 0..127  via lB[row<<6]

  float v0 = 0.f, v1 = 0.f, v2 = 0.f, v3 = 0.f;   // membrane
  float c0 = 0.f, c1 = 0.f, c2 = 0.f, c3 = 0.f;   // synaptic current
  int   n0 = 0,   n1 = 0,   n2 = 0,   n3 = 0;     // spike counts
  unsigned long long mA = 0, mBm = 0, mC = 0, mD = 0;  // prev-step ballot masks

  const XT* xrow = xw + (size_t)b * T * H + (ln << 2);
  float4 xa = XConv<XT>::load4(xrow);
  float4 xb = XConv<XT>::load4(xrow + H);
  const XT* xn = xrow + 2 * H;   // incremental prefetch pointer (t+2)

#pragma unroll 1
  for (int tt = 0; tt < T; ++tt) {
    const float4 xt = xa;
    xa = xb;
    const bool do_pf = (tt + 2 < T);

    // ---- repack prev-step ballot masks (SALU only) ----
    // lo 32 bits of each mask = rows < 128 (LDS); hi 32 bits = rows >= 128 (L2).
    uint64_t Lx = (uint32_t)mA         | ((uint64_t)(uint32_t)mBm         << 32);
    uint64_t Ly = (uint32_t)mC         | ((uint64_t)(uint32_t)mD          << 32);
    uint64_t Gx = (uint32_t)(mA >> 32) | ((uint64_t)(uint32_t)(mBm >> 32) << 32);
    uint64_t Gy = (uint32_t)(mC >> 32) | ((uint64_t)(uint32_t)(mD  >> 32) << 32);
    int nl = __popcll(Lx) + __popcll(Ly);
    int ng = __popcll(Gx) + __popcll(Gy);

    float r0 = 0.f, r1 = 0.f, r2 = 0.f, r3 = 0.f;

    float4 g0, g1, g2, g3, g4, g5, g6, g7;
    float  q0, q1, q2, q3, q4, q5, q6, q7;
    float4 h0, h1, h2, h3, h4, h5, h6, h7;
    float  u0, u1, u2, u3, u4, u5, u6, u7;

    // Issue first global chunk FIRST (oldest VMEM this iteration).
    const bool anyG = (ng > 0);
    if (anyG) {
      CHUNK8(Gx, Gy, ng, gB, g0,g1,g2,g3,g4,g5,g6,g7, q0,q1,q2,q3,q4,q5,q6,q7);
      ng -= 8;
    }

    // xw prefetch: issued AFTER the gather chunk so the gather's counted
    // vmcnt wait does not force-drain this HBM-latency load. Fenced so the
    // scheduler cannot hoist it back above the gather loads.
    __builtin_amdgcn_sched_barrier(0);
    xb = do_pf ? XConv<XT>::load4(xn) : make_float4(0.f, 0.f, 0.f, 0.f);
    xn += H;
    __builtin_amdgcn_sched_barrier(0);

    // LDS stream (rows < 128): issue + consume per chunk (lgkmcnt domain,
    // independent of the vmcnt loads above).
    while (nl > 0) {
      float4 l0, l1, l2, l3, l4, l5, l6, l7;
      float  s0, s1, s2, s3, s4, s5, s6, s7;
      CHUNK8(Lx, Ly, nl, lB, l0,l1,l2,l3,l4,l5,l6,l7, s0,s1,s2,s3,s4,s5,s6,s7);
      nl -= 8;
      ACC8(l0,l1,l2,l3,l4,l5,l6,l7, s0,s1,s2,s3,s4,s5,s6,s7);
    }

    // Global stream (rows >= 128): 2-deep software pipeline. In the common
    // ng<=8 case this is just ACC of the already-issued chunk, waiting only
    // on its own (older-than-xb) loads.
    if (anyG) {
      for (;;) {
        if (ng <= 0) { ACC8(g0,g1,g2,g3,g4,g5,g6,g7, q0,q1,q2,q3,q4,q5,q6,q7); break; }
        CHUNK8(Gx, Gy, ng, gB, h0,h1,h2,h3,h4,h5,h6,h7, u0,u1,u2,u3,u4,u5,u6,u7);
        ng -= 8;
        ACC8(g0,g1,g2,g3,g4,g5,g6,g7, q0,q1,q2,q3,q4,q5,q6,q7);
        if (ng <= 0) { ACC8(h0,h1,h2,h3,h4,h5,h6,h7, u0,u1,u2,u3,u4,u5,u6,u7); break; }
        CHUNK8(Gx, Gy, ng, gB, g0,g1,g2,g3,g4,g5,g6,g7, q0,q1,q2,q3,q4,q5,q6,q7);
        ng -= 8;
        ACC8(h0,h1,h2,h3,h4,h5,h6,h7, u0,u1,u2,u3,u4,u5,u6,u7);
      }
    }

    // ---- LIF update (identical op order to previous absmax-0 kernel) ----
    const float vd0 = v0 + DT_TAU_MEM * (c0 - v0);
    const float vd1 = v1 + DT_TAU_MEM * (c1 - v1);
    const float vd2 = v2 + DT_TAU_MEM * (c2 - v2);
    const float vd3 = v3 + DT_TAU_MEM * (c3 - v3);
    const int z0 = vd0 > V_THRESH;
    const int z1 = vd1 > V_THRESH;
    const int z2 = vd2 > V_THRESH;
    const int z3 = vd3 > V_THRESH;
    v0 = z0 ? 0.f : vd0;  v1 = z1 ? 0.f : vd1;
    v2 = z2 ? 0.f : vd2;  v3 = z3 ? 0.f : vd3;
    c0 = c0 * SYN_DECAY + xt.x + r0;
    c1 = c1 * SYN_DECAY + xt.y + r1;
    c2 = c2 * SYN_DECAY + xt.z + r2;
    c3 = c3 * SYN_DECAY + xt.w + r3;
    n0 += z0; n1 += z1; n2 += z2; n3 += z3;

    mA  = __ballot(z0);  // neurons 4t+0 -> bit t
    mBm = __ballot(z1);  // neurons 4t+1
    mC  = __ballot(z2);  // neurons 4t+2
    mD  = __ballot(z3);  // neurons 4t+3
  }

  // ---- Readout: out[b][o] = sum_h count[h] * fc_w[o][h] + fc_b[o] ----
  const float4 f0 = *reinterpret_cast<const float4*>(fc_w + 0 * H + (ln << 2));
  const float4 f1 = *reinterpret_cast<const float4*>(fc_w + 1 * H + (ln << 2));
  float p0 = (float)n0 * f0.x + (float)n1 * f0.y + (float)n2 * f0.z + (float)n3 * f0.w;
  float p1 = (float)n0 * f1.x + (float)n1 * f1.y + (float)n2 * f1.z + (float)n3 * f1.w;
#pragma unroll
  for (int off = 32; off > 0; off >>= 1) {
    p0 += __shfl_down(p0, off, 64);
    p1 += __shfl_down(p1, off, 64);
  }
  if (ln == 0) {
    out[b * O + 0] = p0 + fc_b[0];
    out[b * O + 1] = p1 + fc_b[1];
  }
}

// ---------------------------------------------------------------------------
extern "C" void kernel_launch(void* const* d_in, const int* in_sizes, int n_in,
                              void* d_out, int out_size, void* d_ws, size_t ws_size,
                              hipStream_t stream) {
  const float* x     = (const float*)d_in[0];
  const float* w_in  = (const float*)d_in[1];
  const float* w_rec = (const float*)d_in[2];
  const float* fc_w  = (const float*)d_in[3];
  const float* fc_b  = (const float*)d_in[4];
  float* out = (float*)d_out;

  // workspace layout: [wT fp32 256KB][xw (fp32 if it fits, else bf16)]
  float* wT = (float*)d_ws;
  const size_t wT_bytes = (size_t)H * H * sizeof(float);
  char* xw_base = (char*)d_ws + wT_bytes;
  const size_t xw_elems = (size_t)B * T * H;
  const bool use_f32 = ws_size >= wT_bytes + xw_elems * sizeof(float);

  transpose_wrec<<<H, H, 0, stream>>>(w_rec, wT);

  if (use_f32) {
    float* xw = (float*)xw_base;
    gemm_xw<float><<<dim3(B * T / 64, H / 64), 256, 0, stream>>>(x, w_in, xw);
    scan_lif<float><<<B, 64, 0, stream>>>(xw, wT, fc_w, fc_b, out);
  } else {
    __hip_bfloat16* xw = (__hip_bfloat16*)xw_base;
    gemm_xw<__hip_bfloat16><<<dim3(B * T / 64, H / 64), 256, 0, stream>>>(x, w_in, xw);
    scan_lif<__hip_bfloat16><<<B, 64, 0, stream>>>(xw, wT, fc_w, fc_b, out);
  }
}

// Round 5
// 1405.674 us; speedup vs baseline: 1.0027x; 1.0027x over previous
//
#include <hip/hip_runtime.h>
#include <hip/hip_bf16.h>
#include <stdint.h>

// Problem constants (SNNExoplanetDetector): B=256 batch, T=1000 steps,
// F=128 input feats, H=256 hidden, O=2 outputs.
constexpr int B = 256, T = 1000, F = 128, H = 256, O = 2;
constexpr float DT_TAU_MEM = 0.1f;   // DT * TAU_MEM_INV
constexpr float SYN_DECAY  = 0.8f;   // 1 - DT * TAU_SYN_INV
constexpr float V_THRESH   = 1.0f;

// ---------------------------------------------------------------------------
// Storage-type adapters for xw (fp32 if workspace fits it, else bf16).
// ---------------------------------------------------------------------------
__device__ inline unsigned short f2bf_raw(float f) {
  __hip_bfloat16 b = __float2bfloat16(f);
  return *reinterpret_cast<unsigned short*>(&b);
}

template <typename XT> struct XConv;
template <> struct XConv<float> {
  static __device__ inline float load1(const float* p) { return *p; }
  static __device__ inline void store4(float* p, float a, float b, float c, float d) {
    *reinterpret_cast<float4*>(p) = make_float4(a, b, c, d);
  }
};
template <> struct XConv<__hip_bfloat16> {
  static __device__ inline float load1(const __hip_bfloat16* p) {
    unsigned u = *reinterpret_cast<const unsigned short*>(p);
    return __uint_as_float(u << 16);
  }
  static __device__ inline void store4(__hip_bfloat16* p, float a, float b, float c, float d) {
    ushort4 u = make_ushort4(f2bf_raw(a), f2bf_raw(b), f2bf_raw(c), f2bf_raw(d));
    *reinterpret_cast<ushort4*>(p) = u;
  }
};

// ---------------------------------------------------------------------------
// Transpose w_rec [h][k] -> wT [k][h]  (so a spike k gathers a contiguous row)
// ---------------------------------------------------------------------------
__global__ void transpose_wrec(const float* __restrict__ w, float* __restrict__ wT) {
  int k = blockIdx.x;
  int h = threadIdx.x;
  wT[k * H + h] = w[h * H + k];
}

// ---------------------------------------------------------------------------
// GEMM: xw[m][n] = sum_k x[m][k] * w_in[n][k];  M = B*T = 256000, K=128, N=256
// (unchanged)
// ---------------------------------------------------------------------------
template <typename XT>
__global__ __launch_bounds__(256) void gemm_xw(const float* __restrict__ x,
                                               const float* __restrict__ w_in,
                                               XT* __restrict__ xw) {
  constexpr int K = 128;
  constexpr int SA = 68;  // padded LDS row stride (floats), multiple of 4 for b128
  __shared__ float As[K][SA];
  __shared__ float Bs[K][SA];

  const int m0 = blockIdx.x * 64;
  const int n0 = blockIdx.y * 64;
  const int tid = threadIdx.x;

  {
    const int r  = tid >> 2;   // 0..63  (row within tile)
    const int cq = tid & 3;    // 0..3   (float4 phase)
    const float* xa = x    + (size_t)(m0 + r) * K;
    const float* xb = w_in + (size_t)(n0 + r) * K;
#pragma unroll
    for (int j = 0; j < 8; ++j) {
      const int c = (cq + (j << 2)) << 2;  // 0..124, step covers all 128
      float4 av = *reinterpret_cast<const float4*>(xa + c);
      float4 bv = *reinterpret_cast<const float4*>(xb + c);
      As[c + 0][r] = av.x; As[c + 1][r] = av.y; As[c + 2][r] = av.z; As[c + 3][r] = av.w;
      Bs[c + 0][r] = bv.x; Bs[c + 1][r] = bv.y; Bs[c + 2][r] = bv.z; Bs[c + 3][r] = bv.w;
    }
  }
  __syncthreads();

  const int tn = (tid & 15) << 2;  // 0,4,...,60
  const int tm = (tid >> 4) << 2;  // 0,4,...,60
  float acc[4][4] = {};

#pragma unroll 16
  for (int k = 0; k < K; ++k) {
    float4 a = *reinterpret_cast<const float4*>(&As[k][tm]);
    float4 b = *reinterpret_cast<const float4*>(&Bs[k][tn]);
    acc[0][0] += a.x * b.x; acc[0][1] += a.x * b.y; acc[0][2] += a.x * b.z; acc[0][3] += a.x * b.w;
    acc[1][0] += a.y * b.x; acc[1][1] += a.y * b.y; acc[1][2] += a.y * b.z; acc[1][3] += a.y * b.w;
    acc[2][0] += a.z * b.x; acc[2][1] += a.z * b.y; acc[2][2] += a.z * b.z; acc[2][3] += a.z * b.w;
    acc[3][0] += a.w * b.x; acc[3][1] += a.w * b.y; acc[3][2] += a.w * b.z; acc[3][3] += a.w * b.w;
  }

#pragma unroll
  for (int im = 0; im < 4; ++im) {
    XT* p = xw + (size_t)(m0 + tm + im) * H + (n0 + tn);
    XConv<XT>::store4(p, acc[im][0], acc[im][1], acc[im][2], acc[im][3]);
  }
}

// ---------------------------------------------------------------------------
// LIF scan v3: 4 waves per batch, column-split, ballot-mask spike exchange.
//   - thread tid owns neuron h=tid (scalar v, i). Wave w ballots its 64
//     neurons -> 4x u64 masks, exchanged via 64B LDS (double-buffered),
//     exactly ONE __syncthreads per step. No atomics, no spike lists.
//   - gather: row extraction on the SALU (readfirstlane'd masks -> s_ff1),
//     per-row load is a scalar 4B read of wT[row][tid]: rows<128 from a
//     128KB LDS stage, rows>=128 from L2. Both coalesced per wave.
//   - per-wave fmac count = ~c/step (scalar), 4x less than the single-wave
//     float4 design; 4 waves work concurrently -> per-step critical path
//     ~4x shorter.
//   - xw loads bursted 8 steps at a time (T=1000=8*125, static unroll) so
//     conservative vmcnt(0) drains in the gather hit an empty HBM queue.
// ---------------------------------------------------------------------------

__device__ __forceinline__ uint64_t rl64(uint64_t v) {
  unsigned lo = __builtin_amdgcn_readfirstlane((unsigned)(v & 0xffffffffull));
  unsigned hi = __builtin_amdgcn_readfirstlane((unsigned)(v >> 32));
  return ((uint64_t)hi << 32) | lo;
}

// Extract one row (0..127) from a 2x64-bit mask stream: X covers rows 0..63,
// Y covers rows 64..127. ctz guard = TOP bit: nonzero masks unaffected;
// empty-empty decodes row 127 (in-bounds, predicated off).
#define EXS(X, Y, ROW) do {                                          \
    uint64_t sel_ = (X) ? (X) : (Y);                                 \
    int p_ = __builtin_ctzll(sel_ | 0x8000000000000000ull);          \
    ROW = p_ + ((X) ? 0 : 64);                                       \
    uint64_t cl_ = sel_ & (sel_ - 1ull);                             \
    Y = (X) ? (Y) : cl_;                                             \
    X = (X) ? cl_ : (X);                                             \
  } while (0)

// Extract up to 8 rows, issue 8 scalar loads BASE[row<<8], preds from N.
#define CH8(X, Y, N, BASE, V0,V1,V2,V3,V4,V5,V6,V7, P0,P1,P2,P3,P4,P5,P6,P7) do { \
    int r_;                                                           \
    P0 = ((N) > 0) ? 1.f : 0.f; EXS(X, Y, r_); V0 = (BASE)[r_ << 8]; \
    P1 = ((N) > 1) ? 1.f : 0.f; EXS(X, Y, r_); V1 = (BASE)[r_ << 8]; \
    P2 = ((N) > 2) ? 1.f : 0.f; EXS(X, Y, r_); V2 = (BASE)[r_ << 8]; \
    P3 = ((N) > 3) ? 1.f : 0.f; EXS(X, Y, r_); V3 = (BASE)[r_ << 8]; \
    P4 = ((N) > 4) ? 1.f : 0.f; EXS(X, Y, r_); V4 = (BASE)[r_ << 8]; \
    P5 = ((N) > 5) ? 1.f : 0.f; EXS(X, Y, r_); V5 = (BASE)[r_ << 8]; \
    P6 = ((N) > 6) ? 1.f : 0.f; EXS(X, Y, r_); V6 = (BASE)[r_ << 8]; \
    P7 = ((N) > 7) ? 1.f : 0.f; EXS(X, Y, r_); V7 = (BASE)[r_ << 8]; \
  } while (0)

#define AC8(V0,V1,V2,V3,V4,V5,V6,V7, P0,P1,P2,P3,P4,P5,P6,P7) do {   \
    r0 += P0 * V0; r1 += P1 * V1; r2 += P2 * V2; r3 += P3 * V3;      \
    r0 += P4 * V4; r1 += P5 * V5; r2 += P6 * V6; r3 += P7 * V7;      \
  } while (0)

// One LIF step. J in 0..7 (compile-time): mask buffer parity.
#define STEP(J, XTV) do {                                                     \
    uint64_t M0 = rl64(msk[((J)&1)^1][0]);                                    \
    uint64_t M1 = rl64(msk[((J)&1)^1][1]);                                    \
    uint64_t M2 = rl64(msk[((J)&1)^1][2]);                                    \
    uint64_t M3 = rl64(msk[((J)&1)^1][3]);                                    \
    int nl = __popcll(M0) + __popcll(M1);                                     \
    int ng = __popcll(M2) + __popcll(M3);                                     \
    float r0 = 0.f, r1 = 0.f, r2 = 0.f, r3 = 0.f;                             \
    float ga0,ga1,ga2,ga3,ga4,ga5,ga6,ga7;                                    \
    float qa0,qa1,qa2,qa3,qa4,qa5,qa6,qa7;                                    \
    float gb0,gb1,gb2,gb3,gb4,gb5,gb6,gb7;                                    \
    float qb0,qb1,qb2,qb3,qb4,qb5,qb6,qb7;                                    \
    const bool anyG = (ng > 0);                                               \
    if (anyG) {                                                               \
      CH8(M2,M3,ng,gBase, ga0,ga1,ga2,ga3,ga4,ga5,ga6,ga7,                    \
          qa0,qa1,qa2,qa3,qa4,qa5,qa6,qa7);                                   \
      ng -= 8;                                                                \
    }                                                                         \
    if (nl > 0) {                                                             \
      float la0,la1,la2,la3,la4,la5,la6,la7;                                  \
      float sa0,sa1,sa2,sa3,sa4,sa5,sa6,sa7;                                  \
      float lb0,lb1,lb2,lb3,lb4,lb5,lb6,lb7;                                  \
      float sb0,sb1,sb2,sb3,sb4,sb5,sb6,sb7;                                  \
      CH8(M0,M1,nl,lBase, la0,la1,la2,la3,la4,la5,la6,la7,                    \
          sa0,sa1,sa2,sa3,sa4,sa5,sa6,sa7);                                   \
      nl -= 8;                                                                \
      for (;;) {                                                              \
        if (nl <= 0) { AC8(la0,la1,la2,la3,la4,la5,la6,la7,                   \
                           sa0,sa1,sa2,sa3,sa4,sa5,sa6,sa7); break; }         \
        CH8(M0,M1,nl,lBase, lb0,lb1,lb2,lb3,lb4,lb5,lb6,lb7,                  \
            sb0,sb1,sb2,sb3,sb4,sb5,sb6,sb7);                                 \
        nl -= 8;                                                              \
        AC8(la0,la1,la2,la3,la4,la5,la6,la7,                                  \
            sa0,sa1,sa2,sa3,sa4,sa5,sa6,sa7);                                 \
        if (nl <= 0) { AC8(lb0,lb1,lb2,lb3,lb4,lb5,lb6,lb7,                   \
                           sb0,sb1,sb2,sb3,sb4,sb5,sb6,sb7); break; }         \
        CH8(M0,M1,nl,lBase, la0,la1,la2,la3,la4,la5,la6,la7,                  \
            sa0,sa1,sa2,sa3,sa4,sa5,sa6,sa7);                                 \
        nl -= 8;                                                              \
        AC8(lb0,lb1,lb2,lb3,lb4,lb5,lb6,lb7,                                  \
            sb0,sb1,sb2,sb3,sb4,sb5,sb6,sb7);                                 \
      }                                                                       \
    }                                                                         \
    if (anyG) {                                                               \
      for (;;) {                                                              \
        if (ng <= 0) { AC8(ga0,ga1,ga2,ga3,ga4,ga5,ga6,ga7,                   \
                           qa0,qa1,qa2,qa3,qa4,qa5,qa6,qa7); break; }         \
        CH8(M2,M3,ng,gBase, gb0,gb1,gb2,gb3,gb4,gb5,gb6,gb7,                  \
            qb0,qb1,qb2,qb3,qb4,qb5,qb6,qb7);                                 \
        ng -= 8;                                                              \
        AC8(ga0,ga1,ga2,ga3,ga4,ga5,ga6,ga7,                                  \
            qa0,qa1,qa2,qa3,qa4,qa5,qa6,qa7);                                 \
        if (ng <= 0) { AC8(gb0,gb1,gb2,gb3,gb4,gb5,gb6,gb7,                   \
                           qb0,qb1,qb2,qb3,qb4,qb5,qb6,qb7); break; }         \
        CH8(M2,M3,ng,gBase, ga0,ga1,ga2,ga3,ga4,ga5,ga6,ga7,                  \
            qa0,qa1,qa2,qa3,qa4,qa5,qa6,qa7);                                 \
        ng -= 8;                                                              \
        AC8(gb0,gb1,gb2,gb3,gb4,gb5,gb6,gb7,                                  \
            qb0,qb1,qb2,qb3,qb4,qb5,qb6,qb7);                                 \
      }                                                                       \
    }                                                                         \
    const float rec = (r0 + r1) + (r2 + r3);                                  \
    const float vd = v + DT_TAU_MEM * (cur - v);                              \
    const int z = vd > V_THRESH;                                              \
    v = z ? 0.f : vd;                                                         \
    cur = cur * SYN_DECAY + (XTV) + rec;                                      \
    ncnt += z;                                                                \
    unsigned long long bz = __ballot(z);                                      \
    if (ln == 0) msk[(J)&1][w] = bz;                                          \
    __syncthreads();                                                          \
  } while (0)

template <typename XT>
__global__ __launch_bounds__(256, 1) void scan_lif(const XT* __restrict__ xw,
                                                   const float* __restrict__ wT,
                                                   const float* __restrict__ fc_w,
                                                   const float* __restrict__ fc_b,
                                                   float* __restrict__ out) {
  const int b   = blockIdx.x;
  const int tid = threadIdx.x;  // owns neuron h = tid
  const int w   = tid >> 6;     // wave 0..3
  const int ln  = tid & 63;

  __shared__ float wlds[128 * 256];          // wT rows 0..127, exact fp32 (128 KiB)
  __shared__ unsigned long long msk[2][4];   // double-buffered ballot masks
  __shared__ float red[8];

  {
    const float4* srcv = reinterpret_cast<const float4*>(wT);
    float4* dstv = reinterpret_cast<float4*>(wlds);
    for (int i = tid; i < 8192; i += 256) dstv[i] = srcv[i];
  }
  if (tid < 4) msk[1][tid] = 0ull;  // step 0 reads buffer 1 (empty spikes)

  const float* lBase = wlds + tid;         // rows 0..127  via lBase[row<<8]
  const float* gBase = wT + 32768 + tid;   // rows 128..255 via gBase[row<<8]

  float v = 0.f, cur = 0.f;
  int ncnt = 0;

  // xw burst registers: 8 steps per block, statically unrolled (T = 8*125).
  const XT* xrow = xw + (size_t)b * T * H + tid;
  float xc0 = XConv<XT>::load1(xrow + 0 * H);
  float xc1 = XConv<XT>::load1(xrow + 1 * H);
  float xc2 = XConv<XT>::load1(xrow + 2 * H);
  float xc3 = XConv<XT>::load1(xrow + 3 * H);
  float xc4 = XConv<XT>::load1(xrow + 4 * H);
  float xc5 = XConv<XT>::load1(xrow + 5 * H);
  float xc6 = XConv<XT>::load1(xrow + 6 * H);
  float xc7 = XConv<XT>::load1(xrow + 7 * H);
  float xn0, xn1, xn2, xn3, xn4, xn5, xn6, xn7;

  __syncthreads();  // wlds + msk init visible

  for (int blk = 0; blk < 125; ++blk) {
    if (blk < 124) {
      const XT* nx = xrow + (size_t)(blk + 1) * 8 * H;
      xn0 = XConv<XT>::load1(nx + 0 * H);
      xn1 = XConv<XT>::load1(nx + 1 * H);
      xn2 = XConv<XT>::load1(nx + 2 * H);
      xn3 = XConv<XT>::load1(nx + 3 * H);
      xn4 = XConv<XT>::load1(nx + 4 * H);
      xn5 = XConv<XT>::load1(nx + 5 * H);
      xn6 = XConv<XT>::load1(nx + 6 * H);
      xn7 = XConv<XT>::load1(nx + 7 * H);
    } else {
      xn0 = xn1 = xn2 = xn3 = xn4 = xn5 = xn6 = xn7 = 0.f;
    }
    STEP(0, xc0); STEP(1, xc1); STEP(2, xc2); STEP(3, xc3);
    STEP(4, xc4); STEP(5, xc5); STEP(6, xc6); STEP(7, xc7);
    xc0 = xn0; xc1 = xn1; xc2 = xn2; xc3 = xn3;
    xc4 = xn4; xc5 = xn5; xc6 = xn6; xc7 = xn7;
  }

  // ---- Readout: out[b][o] = sum_h count[h] * fc_w[o][h] + fc_b[o] ----
  const float cf = (float)ncnt;
#pragma unroll
  for (int o = 0; o < O; ++o) {
    float p = cf * fc_w[o * H + tid];
#pragma unroll
    for (int off = 32; off > 0; off >>= 1) p += __shfl_down(p, off, 64);
    if (ln == 0) red[o * 4 + w] = p;
    __syncthreads();
  }
  if (tid < O) {
    out[b * O + tid] =
        (red[tid * 4 + 0] + red[tid * 4 + 1] + red[tid * 4 + 2] + red[tid * 4 + 3]) + fc_b[tid];
  }
}

// ---------------------------------------------------------------------------
extern "C" void kernel_launch(void* const* d_in, const int* in_sizes, int n_in,
                              void* d_out, int out_size, void* d_ws, size_t ws_size,
                              hipStream_t stream) {
  const float* x     = (const float*)d_in[0];
  const float* w_in  = (const float*)d_in[1];
  const float* w_rec = (const float*)d_in[2];
  const float* fc_w  = (const float*)d_in[3];
  const float* fc_b  = (const float*)d_in[4];
  float* out = (float*)d_out;

  // workspace layout: [wT fp32 256KB][xw (fp32 if it fits, else bf16)]
  float* wT = (float*)d_ws;
  const size_t wT_bytes = (size_t)H * H * sizeof(float);
  char* xw_base = (char*)d_ws + wT_bytes;
  const size_t xw_elems = (size_t)B * T * H;
  const bool use_f32 = ws_size >= wT_bytes + xw_elems * sizeof(float);

  transpose_wrec<<<H, H, 0, stream>>>(w_rec, wT);

  if (use_f32) {
    float* xw = (float*)xw_base;
    gemm_xw<float><<<dim3(B * T / 64, H / 64), 256, 0, stream>>>(x, w_in, xw);
    scan_lif<float><<<B, 256, 0, stream>>>(xw, wT, fc_w, fc_b, out);
  } else {
    __hip_bfloat16* xw = (__hip_bfloat16*)xw_base;
    gemm_xw<__hip_bfloat16><<<dim3(B * T / 64, H / 64), 256, 0, stream>>>(x, w_in, xw);
    scan_lif<__hip_bfloat16><<<B, 256, 0, stream>>>(xw, wT, fc_w, fc_b, out);
  }
}